// Round 1
// baseline (722.240 us; speedup 1.0000x reference)
//
#include <hip/hip_runtime.h>
#include <math.h>

#define BATCH 4
#define NPTS  2048
#define PTS   8192      // BATCH*NPTS
#define NS    64
#define KPTS  15
#define CKP   64
#define FDIM  256
#define HIDD  512
#define NHEAD 8
#define DHEAD 32
#define NLAY  2
#define R2    0.04f
#define KPE   0.08f
#define WIN   0.25f
#define EPSF  1e-5f
#define SCALE 0.17677669529663687f   // 1/sqrt(32)

// ---------------- ball query: first 64 in-radius neighbors, ascending index ----
__global__ void ball_query_k(const float* __restrict__ pos, int* __restrict__ idx)
{
    int p = blockIdx.x;            // global point
    int b = p >> 11;               // NPTS = 2048
    int lane = threadIdx.x;        // 64 threads = 1 wave
    const float* pb = pos + (size_t)b * NPTS * 3;
    float xi = pos[p*3+0], yi = pos[p*3+1], zi = pos[p*3+2];
    int count = 0;
    for (int jc = 0; jc < NPTS; jc += 64) {
        int j = jc + lane;
        float dx = pb[j*3+0] - xi;
        float dy = pb[j*3+1] - yi;
        float dz = pb[j*3+2] - zi;
        float d2 = dx*dx + dy*dy + dz*dz;
        bool within = d2 <= R2;
        unsigned long long m = __ballot(within);
        if (within) {
            int r = count + __popcll(m & ((1ull << lane) - 1ull));
            if (r < NS) idx[p*NS + r] = b*NPTS + j;
        }
        count += __popcll(m);
        if (count >= NS) break;    // uniform across wave
    }
    int c = count < NS ? count : NS;
    if (lane >= c) idx[p*NS + lane] = PTS;   // pad
}

// ---------------- KPConv raw output [P,64] ----------------
__global__ void kpconv_k(const float* __restrict__ pos, const float* __restrict__ feat,
                         const int* __restrict__ idx, const float* __restrict__ kpts,
                         const float* __restrict__ kpw, float* __restrict__ raw)
{
    int wave = threadIdx.x >> 6, lane = threadIdx.x & 63;
    int p = blockIdx.x * 4 + wave;
    __shared__ float wf[4][45];
    __shared__ float kp[45];
    if (threadIdx.x < 45) kp[threadIdx.x] = kpts[threadIdx.x];
    __syncthreads();
    int id = idx[p*NS + lane];
    bool val = id < PTS;
    float cx = pos[p*3+0], cy = pos[p*3+1], cz = pos[p*3+2];
    float rx, ry, rz, f0, f1, f2;
    if (val) {
        rx = pos[id*3+0] - cx; ry = pos[id*3+1] - cy; rz = pos[id*3+2] - cz;
        f0 = feat[id*3+0]; f1 = feat[id*3+1]; f2 = feat[id*3+2];
    } else {
        rx = 1e6f; ry = 1e6f; rz = 1e6f; f0 = f1 = f2 = 0.f;
    }
    for (int k = 0; k < KPTS; ++k) {
        float dx = rx - kp[k*3+0], dy = ry - kp[k*3+1], dz = rz - kp[k*3+2];
        float dist = sqrtf(dx*dx + dy*dy + dz*dz + 1e-12f);
        float infl = 1.0f - dist / KPE;
        infl = infl > 0.f ? infl : 0.f;
        float v0 = infl*f0, v1 = infl*f1, v2 = infl*f2;
        for (int off = 32; off; off >>= 1) {
            v0 += __shfl_down(v0, off);
            v1 += __shfl_down(v1, off);
            v2 += __shfl_down(v2, off);
        }
        if (lane == 0) { wf[wave][k*3+0]=v0; wf[wave][k*3+1]=v1; wf[wave][k*3+2]=v2; }
    }
    __syncthreads();
    float acc = 0.f;
    for (int t = 0; t < 45; ++t) acc += wf[wave][t] * kpw[t*CKP + lane];
    raw[p*CKP + lane] = acc;
}

// ---------------- BN stats: per-channel sum & sumsq over P ----------------
__global__ void bn_stats_k(const float* __restrict__ raw, float* __restrict__ stats)
{
    int c = blockIdx.x, tid = threadIdx.x;
    float s = 0.f, q = 0.f;
    for (int p = tid; p < PTS; p += 256) { float v = raw[p*CKP + c]; s += v; q += v*v; }
    __shared__ float sh[256], sh2[256];
    sh[tid]=s; sh2[tid]=q; __syncthreads();
    for (int o = 128; o; o >>= 1) { if (tid < o) { sh[tid]+=sh[tid+o]; sh2[tid]+=sh2[tid+o]; } __syncthreads(); }
    if (tid == 0) { stats[c] = sh[0]; stats[CKP + c] = sh2[0]; }
}

// ---------------- BN + LeakyReLU + [pos|kpf] @ Wm -> x [P,256] ----------------
__global__ void embed_k(const float* __restrict__ pos, const float* __restrict__ raw,
                        const float* __restrict__ stats, const float* __restrict__ gamma,
                        const float* __restrict__ beta, const float* __restrict__ Wm,
                        float* __restrict__ x)
{
    int p = blockIdx.x, tid = threadIdx.x;
    __shared__ float pw[67];
    if (tid < 3) pw[tid] = pos[p*3 + tid];
    else if (tid < 67) {
        int c = tid - 3;
        float mu  = stats[c] * (1.0f/PTS);
        float var = stats[CKP+c] * (1.0f/PTS) - mu*mu;
        float v = raw[p*CKP + c];
        float h = gamma[c] * (v - mu) * rsqrtf(var + EPSF) + beta[c];
        pw[tid] = h >= 0.f ? h : 0.2f * h;
    }
    __syncthreads();
    float acc = 0.f;
    for (int c = 0; c < 67; ++c) acc += pw[c] * Wm[c*FDIM + tid];
    x[(size_t)p*FDIM + tid] = acc;
}

// ---------------- per-batch min over positions ----------------
__global__ void bmin_k(const float* __restrict__ pos, float* __restrict__ start)
{
    int b = blockIdx.x, tid = threadIdx.x;
    float mx=1e30f, my=1e30f, mz=1e30f;
    for (int n = tid; n < NPTS; n += 256) {
        const float* q = pos + ((size_t)b*NPTS + n)*3;
        mx = fminf(mx, q[0]); my = fminf(my, q[1]); mz = fminf(mz, q[2]);
    }
    __shared__ float sx[256], sy[256], sz[256];
    sx[tid]=mx; sy[tid]=my; sz[tid]=mz; __syncthreads();
    for (int o=128;o;o>>=1){ if(tid<o){sx[tid]=fminf(sx[tid],sx[tid+o]);sy[tid]=fminf(sy[tid],sy[tid+o]);sz[tid]=fminf(sz[tid],sz[tid+o]);} __syncthreads(); }
    if (tid==0){ start[b*3+0]=sx[0]; start[b*3+1]=sy[0]; start[b*3+2]=sz[0]; }
}

// ---------------- compact cluster id + histogram ----------------
__global__ void cid_k(const float* __restrict__ pos, const float* __restrict__ start,
                      int* __restrict__ cc, int* __restrict__ hist)
{
    int p = blockIdx.x*256 + threadIdx.x;
    int b = p >> 11;
    int cx = (int)floorf((pos[p*3+0]-start[b*3+0]) / WIN);
    int cy = (int)floorf((pos[p*3+1]-start[b*3+1]) / WIN);
    int cz = (int)floorf((pos[p*3+2]-start[b*3+2]) / WIN);
    int c = (cx<<4) | (cy<<2) | cz;   // cells are in [0,3] each
    cc[p] = c;
    atomicAdd(&hist[b*64 + c], 1);
}

__global__ void scan_k(const int* __restrict__ hist, int* __restrict__ offs)
{
    int b = threadIdx.x;
    if (b < BATCH) {
        int run = 0;
        for (int c = 0; c < 64; ++c) { offs[b*64+c] = run; run += hist[b*64+c]; }
    }
}

__global__ void scatter_k(const int* __restrict__ cc, const int* __restrict__ offs,
                          int* __restrict__ cursor, int* __restrict__ sorted)
{
    int p = blockIdx.x*256 + threadIdx.x;
    int b = p >> 11;
    int c = cc[p];
    int r = atomicAdd(&cursor[b*64+c], 1);
    sorted[b*NPTS + offs[b*64+c] + r] = p;
}

// ---------------- generic fp32 tiled GEMM: C = A@W + bias (+R) (+relu) -------
template<int ACT>
__global__ void gemm_k(const float* __restrict__ A, const float* __restrict__ W,
                       const float* __restrict__ bias, const float* __restrict__ R,
                       float* __restrict__ C, int M, int Nc, int K)
{
    __shared__ float As[16][65];
    __shared__ float Ws[16][65];
    int tid = threadIdx.x;
    int tx = tid & 15, ty = tid >> 4;
    int bm = blockIdx.y * 64, bn = blockIdx.x * 64;
    float acc[4][4] = {};
    for (int k0 = 0; k0 < K; k0 += 16) {
        #pragma unroll
        for (int i = 0; i < 4; ++i) {
            int id = tid + i*256;
            int kk = id & 15, m = id >> 4;
            As[kk][m] = A[(size_t)(bm + m)*K + k0 + kk];
        }
        #pragma unroll
        for (int i = 0; i < 4; ++i) {
            int id = tid + i*256;
            int n = id & 63, kk = id >> 6;
            Ws[kk][n] = W[(size_t)(k0 + kk)*Nc + bn + n];
        }
        __syncthreads();
        #pragma unroll
        for (int kk = 0; kk < 16; ++kk) {
            float a[4], w[4];
            #pragma unroll
            for (int r = 0; r < 4; ++r) a[r] = As[kk][ty*4+r];
            #pragma unroll
            for (int c = 0; c < 4; ++c) w[c] = Ws[kk][tx*4+c];
            #pragma unroll
            for (int r = 0; r < 4; ++r)
                #pragma unroll
                for (int c = 0; c < 4; ++c)
                    acc[r][c] += a[r]*w[c];
        }
        __syncthreads();
    }
    for (int r = 0; r < 4; ++r) {
        int row = bm + ty*4 + r;
        for (int c = 0; c < 4; ++c) {
            int col = bn + tx*4 + c;
            float v = acc[r][c] + bias[col];
            if (R) v += R[(size_t)row*Nc + col];
            if (ACT == 1) v = v > 0.f ? v : 0.f;
            C[(size_t)row*Nc + col] = v;
        }
    }
}

// ---------------- LayerNorm over rows of 256 ----------------
__global__ void ln_k(const float* __restrict__ in, const float* __restrict__ g,
                     const float* __restrict__ bta, float* __restrict__ out)
{
    int row = blockIdx.x, tid = threadIdx.x;
    float v = in[(size_t)row*FDIM + tid];
    __shared__ float s1[256], s2[256];
    s1[tid]=v; s2[tid]=v*v; __syncthreads();
    for (int o=128;o;o>>=1){ if(tid<o){s1[tid]+=s1[tid+o]; s2[tid]+=s2[tid+o];} __syncthreads(); }
    float mu  = s1[0] * (1.0f/FDIM);
    float var = s2[0] * (1.0f/FDIM) - mu*mu;
    out[(size_t)row*FDIM + tid] = g[tid]*(v-mu)*rsqrtf(var+EPSF) + bta[tid];
}

// ---------------- cluster-local attention ----------------
// grid: (64 clusters, NHEAD, BATCH), 128 threads. Online softmax per query row.
__global__ void attn_k(const float* __restrict__ q, const float* __restrict__ k,
                       const float* __restrict__ v, const int* __restrict__ sorted,
                       const int* __restrict__ offs, const int* __restrict__ hist,
                       float* __restrict__ o)
{
    int cci = blockIdx.x, h = blockIdx.y, b = blockIdx.z;
    int Mc = hist[b*64 + cci];
    if (Mc == 0) return;
    int base = b*NPTS + offs[b*64 + cci];
    __shared__ float Ks[128][DHEAD], Vs[128][DHEAD];
    int tid = threadIdx.x;
    for (int r0 = 0; r0 < Mc; r0 += 128) {
        int row = r0 + tid;
        bool act = row < Mc;
        float qr[DHEAD];
        int pr = 0;
        if (act) {
            pr = sorted[base + row];
            #pragma unroll
            for (int d = 0; d < DHEAD; ++d) qr[d] = q[(size_t)pr*FDIM + h*DHEAD + d];
        }
        float m = -3e38f, l = 0.f, acc[DHEAD];
        #pragma unroll
        for (int d = 0; d < DHEAD; ++d) acc[d] = 0.f;
        for (int j0 = 0; j0 < Mc; j0 += 128) {
            int nj = min(128, Mc - j0);
            __syncthreads();
            for (int t = tid; t < nj*DHEAD; t += 128) {
                int jr = t >> 5, d = t & 31;
                int pj = sorted[base + j0 + jr];
                Ks[jr][d] = k[(size_t)pj*FDIM + h*DHEAD + d];
                Vs[jr][d] = v[(size_t)pj*FDIM + h*DHEAD + d];
            }
            __syncthreads();
            if (act) {
                for (int j = 0; j < nj; ++j) {
                    float dot = 0.f;
                    #pragma unroll
                    for (int d = 0; d < DHEAD; ++d) dot += qr[d]*Ks[j][d];
                    float s = dot * SCALE;
                    float mn = fmaxf(m, s);
                    float a = expf(m - mn);
                    float e = expf(s - mn);
                    l = l*a + e;
                    #pragma unroll
                    for (int d = 0; d < DHEAD; ++d) acc[d] = acc[d]*a + e*Vs[j][d];
                    m = mn;
                }
            }
        }
        if (act) {
            float inv = 1.0f / l;
            #pragma unroll
            for (int d = 0; d < DHEAD; ++d)
                o[(size_t)pr*FDIM + h*DHEAD + d] = acc[d]*inv;
        }
    }
}

extern "C" void kernel_launch(void* const* d_in, const int* in_sizes, int n_in,
                              void* d_out, int out_size, void* d_ws, size_t ws_size,
                              hipStream_t stream)
{
    (void)in_sizes; (void)n_in; (void)out_size; (void)ws_size;
    const float* pos  = (const float*)d_in[0];
    const float* feat = (const float*)d_in[1];
    const float* kpts = (const float*)d_in[2];
    const float* kpw  = (const float*)d_in[3];
    const float* bn_g = (const float*)d_in[4];
    const float* bn_b = (const float*)d_in[5];
    const float* Wm   = (const float*)d_in[6];
    const float* Wq   = (const float*)d_in[7];
    const float* bq   = (const float*)d_in[8];
    const float* Wk   = (const float*)d_in[9];
    const float* bk   = (const float*)d_in[10];
    const float* Wv   = (const float*)d_in[11];
    const float* bv   = (const float*)d_in[12];
    const float* Wo   = (const float*)d_in[13];
    const float* bo   = (const float*)d_in[14];
    const float* g1   = (const float*)d_in[15];
    const float* be1  = (const float*)d_in[16];
    const float* W1   = (const float*)d_in[17];
    const float* bb1  = (const float*)d_in[18];
    const float* W2   = (const float*)d_in[19];
    const float* bb2  = (const float*)d_in[20];
    const float* g2   = (const float*)d_in[21];
    const float* be2  = (const float*)d_in[22];

    char* ws = (char*)d_ws;
    const size_t MB = 1024*1024;
    int*   idx    = (int*)(ws + 0);                 // 2 MB
    float* raw    = (float*)(ws + 2*MB);            // 2 MB
    float* stats  = (float*)(ws + 4*MB);            // 512 B
    float* start  = (float*)(ws + 4*MB + 4096);     // 48 B
    int*   cc     = (int*)(ws + 4*MB + 8192);       // 32 KB
    int*   hist   = (int*)(ws + 4*MB + 8192 + 65536);
    int*   offs   = hist + 256;
    int*   cursor = offs + 256;
    int*   sorted = cursor + 256;                   // 32 KB
    float* x    = (float*)(ws + 5*MB);
    float* qb   = (float*)(ws + 13*MB);
    float* kb   = (float*)(ws + 21*MB);
    float* vb   = (float*)(ws + 29*MB);
    float* attn = (float*)(ws + 37*MB);
    float* t1   = (float*)(ws + 45*MB);
    float* x2   = (float*)(ws + 53*MB);
    float* hbuf = qb;   // [P,512] aliases q,k — both dead by FFN time

    hipMemsetAsync(hist, 0, 3*256*sizeof(int), stream);   // hist + offs + cursor

    ball_query_k<<<PTS, 64, 0, stream>>>(pos, idx);
    kpconv_k<<<PTS/4, 256, 0, stream>>>(pos, feat, idx, kpts, kpw, raw);
    bn_stats_k<<<CKP, 256, 0, stream>>>(raw, stats);
    embed_k<<<PTS, 256, 0, stream>>>(pos, raw, stats, bn_g, bn_b, Wm, x);
    bmin_k<<<BATCH, 256, 0, stream>>>(pos, start);
    cid_k<<<PTS/256, 256, 0, stream>>>(pos, start, cc, hist);
    scan_k<<<1, 64, 0, stream>>>(hist, offs);
    scatter_k<<<PTS/256, 256, 0, stream>>>(cc, offs, cursor, sorted);

    dim3 gF(FDIM/64, PTS/64);
    dim3 gH(HIDD/64, PTS/64);
    for (int l = 0; l < NLAY; ++l) {
        const float* Wq_l = Wq + (size_t)l*FDIM*FDIM;
        const float* Wk_l = Wk + (size_t)l*FDIM*FDIM;
        const float* Wv_l = Wv + (size_t)l*FDIM*FDIM;
        const float* Wo_l = Wo + (size_t)l*FDIM*FDIM;
        const float* W1_l = W1 + (size_t)l*FDIM*HIDD;
        const float* W2_l = W2 + (size_t)l*HIDD*FDIM;

        gemm_k<0><<<gF, 256, 0, stream>>>(x, Wq_l, bq + l*FDIM, nullptr, qb, PTS, FDIM, FDIM);
        gemm_k<0><<<gF, 256, 0, stream>>>(x, Wk_l, bk + l*FDIM, nullptr, kb, PTS, FDIM, FDIM);
        gemm_k<0><<<gF, 256, 0, stream>>>(x, Wv_l, bv + l*FDIM, nullptr, vb, PTS, FDIM, FDIM);
        attn_k<<<dim3(64, NHEAD, BATCH), 128, 0, stream>>>(qb, kb, vb, sorted, offs, hist, attn);
        gemm_k<0><<<gF, 256, 0, stream>>>(attn, Wo_l, bo + l*FDIM, x, t1, PTS, FDIM, FDIM);
        ln_k<<<PTS, 256, 0, stream>>>(t1, g1 + l*FDIM, be1 + l*FDIM, x2);
        gemm_k<1><<<gH, 256, 0, stream>>>(x2, W1_l, bb1 + l*HIDD, nullptr, hbuf, PTS, HIDD, FDIM);
        gemm_k<0><<<gF, 256, 0, stream>>>(hbuf, W2_l, bb2 + l*FDIM, x2, t1, PTS, FDIM, HIDD);
        float* dst = (l == NLAY-1) ? (float*)d_out : x;
        ln_k<<<PTS, 256, 0, stream>>>(t1, g2 + l*FDIM, be2 + l*FDIM, dst);
    }
}

// Round 2
// 364.397 us; speedup vs baseline: 1.9820x; 1.9820x over previous
//
#include <hip/hip_runtime.h>
#include <math.h>

#define BATCH 4
#define NPTS  2048
#define PTS   8192      // BATCH*NPTS
#define NS    64
#define KPTS  15
#define CKP   64
#define FDIM  256
#define HIDD  512
#define NHEAD 8
#define DHEAD 32
#define NLAY  2
#define R2    0.04f
#define KPE   0.08f
#define WIN   0.25f
#define EPSF  1e-5f
#define SCALE 0.17677669529663687f   // 1/sqrt(32)

typedef __attribute__((ext_vector_type(8))) short          short8;
typedef __attribute__((ext_vector_type(8))) unsigned short ushort8;
typedef __attribute__((ext_vector_type(4))) float          f32x4;

static __device__ __forceinline__ unsigned short f2bf(float f) {
    unsigned int u = __float_as_uint(f);
    unsigned int r = u + 0x7fffu + ((u >> 16) & 1u);   // RNE
    return (unsigned short)(r >> 16);
}
static __device__ __forceinline__ float b2f(unsigned short u) {
    return __uint_as_float(((unsigned int)u) << 16);
}

// ---------------- ball query: first 64 in-radius neighbors, ascending index ----
__global__ void ball_query_k(const float* __restrict__ pos, int* __restrict__ idx)
{
    int p = blockIdx.x;
    int b = p >> 11;
    int lane = threadIdx.x;
    const float* pb = pos + (size_t)b * NPTS * 3;
    float xi = pos[p*3+0], yi = pos[p*3+1], zi = pos[p*3+2];
    int count = 0;
    for (int jc = 0; jc < NPTS; jc += 64) {
        int j = jc + lane;
        float dx = pb[j*3+0] - xi;
        float dy = pb[j*3+1] - yi;
        float dz = pb[j*3+2] - zi;
        float d2 = dx*dx + dy*dy + dz*dz;
        bool within = d2 <= R2;
        unsigned long long m = __ballot(within);
        if (within) {
            int r = count + __popcll(m & ((1ull << lane) - 1ull));
            if (r < NS) idx[p*NS + r] = b*NPTS + j;
        }
        count += __popcll(m);
        if (count >= NS) break;
    }
    int c = count < NS ? count : NS;
    if (lane >= c) idx[p*NS + lane] = PTS;
}

// ---------------- KPConv raw output [P,64] ----------------
__global__ void kpconv_k(const float* __restrict__ pos, const float* __restrict__ feat,
                         const int* __restrict__ idx, const float* __restrict__ kpts,
                         const float* __restrict__ kpw, float* __restrict__ raw)
{
    int wave = threadIdx.x >> 6, lane = threadIdx.x & 63;
    int p = blockIdx.x * 4 + wave;
    __shared__ float wf[4][45];
    __shared__ float kp[45];
    if (threadIdx.x < 45) kp[threadIdx.x] = kpts[threadIdx.x];
    __syncthreads();
    int id = idx[p*NS + lane];
    bool val = id < PTS;
    float cx = pos[p*3+0], cy = pos[p*3+1], cz = pos[p*3+2];
    float rx, ry, rz, f0, f1, f2;
    if (val) {
        rx = pos[id*3+0] - cx; ry = pos[id*3+1] - cy; rz = pos[id*3+2] - cz;
        f0 = feat[id*3+0]; f1 = feat[id*3+1]; f2 = feat[id*3+2];
    } else {
        rx = 1e6f; ry = 1e6f; rz = 1e6f; f0 = f1 = f2 = 0.f;
    }
    for (int k = 0; k < KPTS; ++k) {
        float dx = rx - kp[k*3+0], dy = ry - kp[k*3+1], dz = rz - kp[k*3+2];
        float dist = sqrtf(dx*dx + dy*dy + dz*dz + 1e-12f);
        float infl = 1.0f - dist / KPE;
        infl = infl > 0.f ? infl : 0.f;
        float v0 = infl*f0, v1 = infl*f1, v2 = infl*f2;
        for (int off = 32; off; off >>= 1) {
            v0 += __shfl_down(v0, off);
            v1 += __shfl_down(v1, off);
            v2 += __shfl_down(v2, off);
        }
        if (lane == 0) { wf[wave][k*3+0]=v0; wf[wave][k*3+1]=v1; wf[wave][k*3+2]=v2; }
    }
    __syncthreads();
    float acc = 0.f;
    for (int t = 0; t < 45; ++t) acc += wf[wave][t] * kpw[t*CKP + lane];
    raw[p*CKP + lane] = acc;
}

// ---------------- BN stats ----------------
__global__ void bn_stats_k(const float* __restrict__ raw, float* __restrict__ stats)
{
    int c = blockIdx.x, tid = threadIdx.x;
    float s = 0.f, q = 0.f;
    for (int p = tid; p < PTS; p += 256) { float v = raw[p*CKP + c]; s += v; q += v*v; }
    __shared__ float sh[256], sh2[256];
    sh[tid]=s; sh2[tid]=q; __syncthreads();
    for (int o = 128; o; o >>= 1) { if (tid < o) { sh[tid]+=sh[tid+o]; sh2[tid]+=sh2[tid+o]; } __syncthreads(); }
    if (tid == 0) { stats[c] = sh[0]; stats[CKP + c] = sh2[0]; }
}

// ---------------- BN + LeakyReLU + [pos|kpf] @ Wm -> x [P,256] (fp32 + bf16) --
__global__ void embed_k(const float* __restrict__ pos, const float* __restrict__ raw,
                        const float* __restrict__ stats, const float* __restrict__ gamma,
                        const float* __restrict__ beta, const float* __restrict__ Wm,
                        float* __restrict__ x, unsigned short* __restrict__ xb)
{
    int p = blockIdx.x, tid = threadIdx.x;
    __shared__ float pw[67];
    if (tid < 3) pw[tid] = pos[p*3 + tid];
    else if (tid < 67) {
        int c = tid - 3;
        float mu  = stats[c] * (1.0f/PTS);
        float var = stats[CKP+c] * (1.0f/PTS) - mu*mu;
        float v = raw[p*CKP + c];
        float h = gamma[c] * (v - mu) * rsqrtf(var + EPSF) + beta[c];
        pw[tid] = h >= 0.f ? h : 0.2f * h;
    }
    __syncthreads();
    float acc = 0.f;
    for (int c = 0; c < 67; ++c) acc += pw[c] * Wm[c*FDIM + tid];
    x[(size_t)p*FDIM + tid] = acc;
    xb[(size_t)p*FDIM + tid] = f2bf(acc);
}

// ---------------- per-batch min ----------------
__global__ void bmin_k(const float* __restrict__ pos, float* __restrict__ start)
{
    int b = blockIdx.x, tid = threadIdx.x;
    float mx=1e30f, my=1e30f, mz=1e30f;
    for (int n = tid; n < NPTS; n += 256) {
        const float* q = pos + ((size_t)b*NPTS + n)*3;
        mx = fminf(mx, q[0]); my = fminf(my, q[1]); mz = fminf(mz, q[2]);
    }
    __shared__ float sx[256], sy[256], sz[256];
    sx[tid]=mx; sy[tid]=my; sz[tid]=mz; __syncthreads();
    for (int o=128;o;o>>=1){ if(tid<o){sx[tid]=fminf(sx[tid],sx[tid+o]);sy[tid]=fminf(sy[tid],sy[tid+o]);sz[tid]=fminf(sz[tid],sz[tid+o]);} __syncthreads(); }
    if (tid==0){ start[b*3+0]=sx[0]; start[b*3+1]=sy[0]; start[b*3+2]=sz[0]; }
}

// ---------------- cluster id + histogram + scan + scatter ----------------
__global__ void cid_k(const float* __restrict__ pos, const float* __restrict__ start,
                      int* __restrict__ cc, int* __restrict__ hist)
{
    int p = blockIdx.x*256 + threadIdx.x;
    int b = p >> 11;
    int cx = (int)floorf((pos[p*3+0]-start[b*3+0]) / WIN);
    int cy = (int)floorf((pos[p*3+1]-start[b*3+1]) / WIN);
    int cz = (int)floorf((pos[p*3+2]-start[b*3+2]) / WIN);
    int c = (cx<<4) | (cy<<2) | cz;
    cc[p] = c;
    atomicAdd(&hist[b*64 + c], 1);
}

__global__ void scan_k(const int* __restrict__ hist, int* __restrict__ offs)
{
    int b = threadIdx.x;
    if (b < BATCH) {
        int run = 0;
        for (int c = 0; c < 64; ++c) { offs[b*64+c] = run; run += hist[b*64+c]; }
    }
}

__global__ void scatter_k(const int* __restrict__ cc, const int* __restrict__ offs,
                          int* __restrict__ cursor, int* __restrict__ sorted)
{
    int p = blockIdx.x*256 + threadIdx.x;
    int b = p >> 11;
    int c = cc[p];
    int r = atomicAdd(&cursor[b*64+c], 1);
    sorted[b*NPTS + offs[b*64+c] + r] = p;
}

// ---------------- weight convert+transpose: [K][N] f32 -> [N][K] bf16 --------
__global__ void wconv_k(const float* __restrict__ Wq, const float* __restrict__ Wk,
                        const float* __restrict__ Wv, const float* __restrict__ Wo,
                        const float* __restrict__ W1, const float* __restrict__ W2,
                        unsigned short* __restrict__ wT)
{
    int id = blockIdx.z; int t = id >> 1, l = id & 1;
    const float* src; unsigned short* dst; int K, N;
    switch (t) {
        case 0: src=Wq+(size_t)l*65536;  dst=wT+(size_t)l*65536;            K=256; N=256; break;
        case 1: src=Wk+(size_t)l*65536;  dst=wT+131072+(size_t)l*65536;     K=256; N=256; break;
        case 2: src=Wv+(size_t)l*65536;  dst=wT+262144+(size_t)l*65536;     K=256; N=256; break;
        case 3: src=Wo+(size_t)l*65536;  dst=wT+393216+(size_t)l*65536;     K=256; N=256; break;
        case 4: src=W1+(size_t)l*131072; dst=wT+524288+(size_t)l*131072;    K=256; N=512; break;
        default:src=W2+(size_t)l*131072; dst=wT+786432+(size_t)l*131072;    K=512; N=256; break;
    }
    int n0 = blockIdx.x*32, k0 = blockIdx.y*32;
    if (n0 >= N || k0 >= K) return;
    __shared__ float ld[32][33];
    int tid = threadIdx.x;
    #pragma unroll
    for (int i = 0; i < 4; ++i) { int v=tid+i*256; int ty=v>>5, tx=v&31;
        ld[ty][tx] = src[(size_t)(k0+ty)*N + n0+tx]; }
    __syncthreads();
    #pragma unroll
    for (int i = 0; i < 4; ++i) { int v=tid+i*256; int ny=v>>5, nk=v&31;
        dst[(size_t)(n0+ny)*K + k0+nk] = f2bf(ld[nk][ny]); }
}

// ---------------- bf16 MFMA GEMM: C = A@Wt^T + bias (+R) (+relu) -------------
// A [M][K] bf16, Wt [N][K] bf16. Tile 64x64x64, 4 waves, wave=32x32 (2x2 frags).
template<int ACT>
__global__ __launch_bounds__(256) void bgemm_k(
    const unsigned short* __restrict__ A, const unsigned short* __restrict__ Wt,
    const float* __restrict__ bias, const float* __restrict__ R,
    float* __restrict__ Cf, unsigned short* __restrict__ Cb,
    int M, int Nc, int K)
{
    __shared__ unsigned short As[64*72];
    __shared__ unsigned short Bs[64*72];
    int tid = threadIdx.x;
    int l = tid & 63, w = tid >> 6;
    int wr = w >> 1, wc = w & 1;
    int lr = l & 15, lk = l >> 4;
    int bm = blockIdx.y * 64, bn = blockIdx.x * 64;

    f32x4 acc[2][2] = {};

    for (int k0 = 0; k0 < K; k0 += 64) {
        __syncthreads();
        #pragma unroll
        for (int i = 0; i < 2; ++i) {
            int id = tid + i*256;
            int row = id >> 3, seg = id & 7;
            ushort8 va = *(const ushort8*)&A[(size_t)(bm + row)*K + k0 + seg*8];
            *(ushort8*)&As[row*72 + seg*8] = va;
            ushort8 vb = *(const ushort8*)&Wt[(size_t)(bn + row)*K + k0 + seg*8];
            *(ushort8*)&Bs[row*72 + seg*8] = vb;
        }
        __syncthreads();
        #pragma unroll
        for (int kk = 0; kk < 64; kk += 32) {
            short8 a[2], b[2];
            #pragma unroll
            for (int mi = 0; mi < 2; ++mi)
                a[mi] = *(const short8*)&As[(wr*32 + mi*16 + lr)*72 + kk + lk*8];
            #pragma unroll
            for (int ni = 0; ni < 2; ++ni)
                b[ni] = *(const short8*)&Bs[(wc*32 + ni*16 + lr)*72 + kk + lk*8];
            #pragma unroll
            for (int mi = 0; mi < 2; ++mi)
                #pragma unroll
                for (int ni = 0; ni < 2; ++ni)
                    acc[mi][ni] = __builtin_amdgcn_mfma_f32_16x16x32_bf16(
                        a[mi], b[ni], acc[mi][ni], 0, 0, 0);
        }
    }

    #pragma unroll
    for (int mi = 0; mi < 2; ++mi) {
        #pragma unroll
        for (int ni = 0; ni < 2; ++ni) {
            #pragma unroll
            for (int r = 0; r < 4; ++r) {
                int row = bm + wr*32 + mi*16 + lk*4 + r;
                int col = bn + wc*32 + ni*16 + lr;
                float v = acc[mi][ni][r] + bias[col];
                if (R)  v += R[(size_t)row*Nc + col];
                if (ACT == 1) v = v > 0.f ? v : 0.f;
                if (Cf) Cf[(size_t)row*Nc + col] = v;
                if (Cb) Cb[(size_t)row*Nc + col] = f2bf(v);
            }
        }
    }
}

// ---------------- LayerNorm over rows of 256 (fp32 out + bf16 out) -----------
__global__ void ln_k(const float* __restrict__ in, const float* __restrict__ g,
                     const float* __restrict__ bta, float* __restrict__ out,
                     unsigned short* __restrict__ outb)
{
    int row = blockIdx.x, tid = threadIdx.x;
    float v = in[(size_t)row*FDIM + tid];
    __shared__ float s1[256], s2[256];
    s1[tid]=v; s2[tid]=v*v; __syncthreads();
    for (int o=128;o;o>>=1){ if(tid<o){s1[tid]+=s1[tid+o]; s2[tid]+=s2[tid+o];} __syncthreads(); }
    float mu  = s1[0] * (1.0f/FDIM);
    float var = s2[0] * (1.0f/FDIM) - mu*mu;
    float r = g[tid]*(v-mu)*rsqrtf(var+EPSF) + bta[tid];
    out[(size_t)row*FDIM + tid] = r;
    outb[(size_t)row*FDIM + tid] = f2bf(r);
}

// ---------------- cluster-local attention (bf16 in, bf16 out) ----------------
__global__ void attn_k(const unsigned short* __restrict__ q, const unsigned short* __restrict__ k,
                       const unsigned short* __restrict__ v, const int* __restrict__ sorted,
                       const int* __restrict__ offs, const int* __restrict__ hist,
                       unsigned short* __restrict__ o)
{
    int cci = blockIdx.x, h = blockIdx.y, b = blockIdx.z;
    int Mc = hist[b*64 + cci];
    if (Mc == 0) return;
    int base = b*NPTS + offs[b*64 + cci];
    __shared__ float Ks[128][DHEAD], Vs[128][DHEAD];
    int tid = threadIdx.x;
    for (int r0 = 0; r0 < Mc; r0 += 128) {
        int row = r0 + tid;
        bool act = row < Mc;
        float qr[DHEAD];
        int pr = 0;
        if (act) {
            pr = sorted[base + row];
            #pragma unroll
            for (int d = 0; d < DHEAD; ++d) qr[d] = b2f(q[(size_t)pr*FDIM + h*DHEAD + d]);
        }
        float m = -3e38f, l = 0.f, acc[DHEAD];
        #pragma unroll
        for (int d = 0; d < DHEAD; ++d) acc[d] = 0.f;
        for (int j0 = 0; j0 < Mc; j0 += 128) {
            int nj = min(128, Mc - j0);
            __syncthreads();
            for (int t = tid; t < nj*DHEAD; t += 128) {
                int jr = t >> 5, d = t & 31;
                int pj = sorted[base + j0 + jr];
                Ks[jr][d] = b2f(k[(size_t)pj*FDIM + h*DHEAD + d]);
                Vs[jr][d] = b2f(v[(size_t)pj*FDIM + h*DHEAD + d]);
            }
            __syncthreads();
            if (act) {
                for (int j = 0; j < nj; ++j) {
                    float dot = 0.f;
                    #pragma unroll
                    for (int d = 0; d < DHEAD; ++d) dot += qr[d]*Ks[j][d];
                    float s = dot * SCALE;
                    float mn = fmaxf(m, s);
                    float a = expf(m - mn);
                    float e = expf(s - mn);
                    l = l*a + e;
                    #pragma unroll
                    for (int d = 0; d < DHEAD; ++d) acc[d] = acc[d]*a + e*Vs[j][d];
                    m = mn;
                }
            }
        }
        if (act) {
            float inv = 1.0f / l;
            #pragma unroll
            for (int d = 0; d < DHEAD; ++d)
                o[(size_t)pr*FDIM + h*DHEAD + d] = f2bf(acc[d]*inv);
        }
    }
}

extern "C" void kernel_launch(void* const* d_in, const int* in_sizes, int n_in,
                              void* d_out, int out_size, void* d_ws, size_t ws_size,
                              hipStream_t stream)
{
    (void)in_sizes; (void)n_in; (void)out_size; (void)ws_size;
    const float* pos  = (const float*)d_in[0];
    const float* feat = (const float*)d_in[1];
    const float* kpts = (const float*)d_in[2];
    const float* kpw  = (const float*)d_in[3];
    const float* bn_g = (const float*)d_in[4];
    const float* bn_b = (const float*)d_in[5];
    const float* Wm   = (const float*)d_in[6];
    const float* Wq   = (const float*)d_in[7];
    const float* bq   = (const float*)d_in[8];
    const float* Wk   = (const float*)d_in[9];
    const float* bk   = (const float*)d_in[10];
    const float* Wv   = (const float*)d_in[11];
    const float* bv   = (const float*)d_in[12];
    const float* Wo   = (const float*)d_in[13];
    const float* bo   = (const float*)d_in[14];
    const float* g1   = (const float*)d_in[15];
    const float* be1  = (const float*)d_in[16];
    const float* W1   = (const float*)d_in[17];
    const float* bb1  = (const float*)d_in[18];
    const float* W2   = (const float*)d_in[19];
    const float* bb2  = (const float*)d_in[20];
    const float* g2   = (const float*)d_in[21];
    const float* be2  = (const float*)d_in[22];

    char* ws = (char*)d_ws;
    const size_t MB = 1024*1024;
    int*   idx    = (int*)(ws + 0);
    float* raw    = (float*)(ws + 2*MB);
    float* stats  = (float*)(ws + 4*MB);
    float* start  = (float*)(ws + 4*MB + 4096);
    int*   cc     = (int*)(ws + 4*MB + 8192);
    int*   hist   = (int*)(ws + 4*MB + 8192 + 65536);
    int*   offs   = hist + 256;
    int*   cursor = offs + 256;
    int*   sorted = cursor + 256;
    float* x    = (float*)(ws + 5*MB);                 // [P,256] f32
    float* t1   = (float*)(ws + 13*MB);                // [P,256] f32
    float* x2   = (float*)(ws + 21*MB);                // [P,256] f32
    unsigned short* xb    = (unsigned short*)(ws + 29*MB);  // [P,256] bf16
    unsigned short* qb    = (unsigned short*)(ws + 33*MB);
    unsigned short* kb    = (unsigned short*)(ws + 37*MB);
    unsigned short* vb    = (unsigned short*)(ws + 41*MB);  // also x2b after attn
    unsigned short* attnb = (unsigned short*)(ws + 45*MB);
    unsigned short* wT    = (unsigned short*)(ws + 49*MB);  // 2 MB of transposed bf16 weights
    unsigned short* hb    = qb;                              // [P,512] bf16 over qb+kb
    unsigned short* x2b   = vb;

    hipMemsetAsync(hist, 0, 3*256*sizeof(int), stream);

    wconv_k<<<dim3(16,16,12), 256, 0, stream>>>(Wq, Wk, Wv, Wo, W1, W2, wT);
    ball_query_k<<<PTS, 64, 0, stream>>>(pos, idx);
    kpconv_k<<<PTS/4, 256, 0, stream>>>(pos, feat, idx, kpts, kpw, raw);
    bn_stats_k<<<CKP, 256, 0, stream>>>(raw, stats);
    embed_k<<<PTS, 256, 0, stream>>>(pos, raw, stats, bn_g, bn_b, Wm, x, xb);
    bmin_k<<<BATCH, 256, 0, stream>>>(pos, start);
    cid_k<<<PTS/256, 256, 0, stream>>>(pos, start, cc, hist);
    scan_k<<<1, 64, 0, stream>>>(hist, offs);
    scatter_k<<<PTS/256, 256, 0, stream>>>(cc, offs, cursor, sorted);

    const unsigned short* WqT = wT;
    const unsigned short* WkT = wT + 131072;
    const unsigned short* WvT = wT + 262144;
    const unsigned short* WoT = wT + 393216;
    const unsigned short* W1T = wT + 524288;
    const unsigned short* W2T = wT + 786432;

    dim3 gF(FDIM/64, PTS/64);   // N=256
    dim3 gH(HIDD/64, PTS/64);   // N=512
    for (int l = 0; l < NLAY; ++l) {
        bgemm_k<0><<<gF, 256, 0, stream>>>(xb, WqT + (size_t)l*65536, bq + l*FDIM,
                                           nullptr, nullptr, qb, PTS, FDIM, FDIM);
        bgemm_k<0><<<gF, 256, 0, stream>>>(xb, WkT + (size_t)l*65536, bk + l*FDIM,
                                           nullptr, nullptr, kb, PTS, FDIM, FDIM);
        bgemm_k<0><<<gF, 256, 0, stream>>>(xb, WvT + (size_t)l*65536, bv + l*FDIM,
                                           nullptr, nullptr, vb, PTS, FDIM, FDIM);
        attn_k<<<dim3(64, NHEAD, BATCH), 128, 0, stream>>>(qb, kb, vb, sorted, offs, hist, attnb);
        bgemm_k<0><<<gF, 256, 0, stream>>>(attnb, WoT + (size_t)l*65536, bo + l*FDIM,
                                           x, t1, nullptr, PTS, FDIM, FDIM);
        ln_k<<<PTS, 256, 0, stream>>>(t1, g1 + l*FDIM, be1 + l*FDIM, x2, x2b);
        bgemm_k<1><<<gH, 256, 0, stream>>>(x2b, W1T + (size_t)l*131072, bb1 + l*HIDD,
                                           nullptr, nullptr, hb, PTS, HIDD, FDIM);
        bgemm_k<0><<<gF, 256, 0, stream>>>(hb, W2T + (size_t)l*131072, bb2 + l*FDIM,
                                           x2, t1, nullptr, PTS, FDIM, HIDD);
        float* dst = (l == NLAY-1) ? (float*)d_out : x;
        ln_k<<<PTS, 256, 0, stream>>>(t1, g2 + l*FDIM, be2 + l*FDIM, dst, xb);
    }
}

// Round 3
// 276.028 us; speedup vs baseline: 2.6165x; 1.3201x over previous
//
#include <hip/hip_runtime.h>
#include <math.h>

#define BATCH 4
#define NPTS  2048
#define PTS   8192      // BATCH*NPTS
#define NS    64
#define KPTS  15
#define CKP   64
#define FDIM  256
#define HIDD  512
#define NHEAD 8
#define DHEAD 32
#define NLAY  2
#define R2    0.04f
#define KPE   0.08f
#define WIN   0.25f
#define EPSF  1e-5f
#define SCALE 0.17677669529663687f   // 1/sqrt(32)
#define CPITCH 264                   // 256 + 8 pad (bank-safe)

typedef __attribute__((ext_vector_type(8))) short          short8;
typedef __attribute__((ext_vector_type(8))) unsigned short ushort8;
typedef __attribute__((ext_vector_type(4))) float          f32x4;

static __device__ __forceinline__ unsigned short f2bf(float f) {
    unsigned int u = __float_as_uint(f);
    unsigned int r = u + 0x7fffu + ((u >> 16) & 1u);   // RNE
    return (unsigned short)(r >> 16);
}
static __device__ __forceinline__ float b2f(unsigned short u) {
    return __uint_as_float(((unsigned int)u) << 16);
}

// ---------------- ball query ----------------
__global__ void ball_query_k(const float* __restrict__ pos, int* __restrict__ idx)
{
    int p = blockIdx.x;
    int b = p >> 11;
    int lane = threadIdx.x;
    const float* pb = pos + (size_t)b * NPTS * 3;
    float xi = pos[p*3+0], yi = pos[p*3+1], zi = pos[p*3+2];
    int count = 0;
    for (int jc = 0; jc < NPTS; jc += 64) {
        int j = jc + lane;
        float dx = pb[j*3+0] - xi;
        float dy = pb[j*3+1] - yi;
        float dz = pb[j*3+2] - zi;
        float d2 = dx*dx + dy*dy + dz*dz;
        bool within = d2 <= R2;
        unsigned long long m = __ballot(within);
        if (within) {
            int r = count + __popcll(m & ((1ull << lane) - 1ull));
            if (r < NS) idx[p*NS + r] = b*NPTS + j;
        }
        count += __popcll(m);
        if (count >= NS) break;
    }
    int c = count < NS ? count : NS;
    if (lane >= c) idx[p*NS + lane] = PTS;
}

// ---------------- KPConv raw output [P,64] ----------------
__global__ void kpconv_k(const float* __restrict__ pos, const float* __restrict__ feat,
                         const int* __restrict__ idx, const float* __restrict__ kpts,
                         const float* __restrict__ kpw, float* __restrict__ raw)
{
    int wave = threadIdx.x >> 6, lane = threadIdx.x & 63;
    int p = blockIdx.x * 4 + wave;
    __shared__ float wf[4][45];
    __shared__ float kp[45];
    if (threadIdx.x < 45) kp[threadIdx.x] = kpts[threadIdx.x];
    __syncthreads();
    int id = idx[p*NS + lane];
    bool val = id < PTS;
    float cx = pos[p*3+0], cy = pos[p*3+1], cz = pos[p*3+2];
    float rx, ry, rz, f0, f1, f2;
    if (val) {
        rx = pos[id*3+0] - cx; ry = pos[id*3+1] - cy; rz = pos[id*3+2] - cz;
        f0 = feat[id*3+0]; f1 = feat[id*3+1]; f2 = feat[id*3+2];
    } else {
        rx = 1e6f; ry = 1e6f; rz = 1e6f; f0 = f1 = f2 = 0.f;
    }
    for (int k = 0; k < KPTS; ++k) {
        float dx = rx - kp[k*3+0], dy = ry - kp[k*3+1], dz = rz - kp[k*3+2];
        float dist = sqrtf(dx*dx + dy*dy + dz*dz + 1e-12f);
        float infl = 1.0f - dist / KPE;
        infl = infl > 0.f ? infl : 0.f;
        float v0 = infl*f0, v1 = infl*f1, v2 = infl*f2;
        for (int off = 32; off; off >>= 1) {
            v0 += __shfl_down(v0, off);
            v1 += __shfl_down(v1, off);
            v2 += __shfl_down(v2, off);
        }
        if (lane == 0) { wf[wave][k*3+0]=v0; wf[wave][k*3+1]=v1; wf[wave][k*3+2]=v2; }
    }
    __syncthreads();
    float acc = 0.f;
    for (int t = 0; t < 45; ++t) acc += wf[wave][t] * kpw[t*CKP + lane];
    raw[p*CKP + lane] = acc;
}

// ---------------- BN stats ----------------
__global__ void bn_stats_k(const float* __restrict__ raw, float* __restrict__ stats)
{
    int c = blockIdx.x, tid = threadIdx.x;
    float s = 0.f, q = 0.f;
    for (int p = tid; p < PTS; p += 256) { float v = raw[p*CKP + c]; s += v; q += v*v; }
    __shared__ float sh[256], sh2[256];
    sh[tid]=s; sh2[tid]=q; __syncthreads();
    for (int o = 128; o; o >>= 1) { if (tid < o) { sh[tid]+=sh[tid+o]; sh2[tid]+=sh2[tid+o]; } __syncthreads(); }
    if (tid == 0) { stats[c] = sh[0]; stats[CKP + c] = sh2[0]; }
}

// ------- BN + LeakyReLU + [pos|kpf] @ Wm -> x written in SORTED order --------
__global__ void embed_k(const float* __restrict__ pos, const float* __restrict__ raw,
                        const float* __restrict__ stats, const float* __restrict__ gamma,
                        const float* __restrict__ beta, const float* __restrict__ Wm,
                        const int* __restrict__ inv,
                        float* __restrict__ xs, unsigned short* __restrict__ xsb)
{
    int p = blockIdx.x, tid = threadIdx.x;
    __shared__ float pw[67];
    if (tid < 3) pw[tid] = pos[p*3 + tid];
    else if (tid < 67) {
        int c = tid - 3;
        float mu  = stats[c] * (1.0f/PTS);
        float var = stats[CKP+c] * (1.0f/PTS) - mu*mu;
        float v = raw[p*CKP + c];
        float h = gamma[c] * (v - mu) * rsqrtf(var + EPSF) + beta[c];
        pw[tid] = h >= 0.f ? h : 0.2f * h;
    }
    __syncthreads();
    float acc = 0.f;
    for (int c = 0; c < 67; ++c) acc += pw[c] * Wm[c*FDIM + tid];
    int slot = inv[p];
    xs[(size_t)slot*FDIM + tid] = acc;
    xsb[(size_t)slot*FDIM + tid] = f2bf(acc);
}

// ---------------- per-batch min ----------------
__global__ void bmin_k(const float* __restrict__ pos, float* __restrict__ start)
{
    int b = blockIdx.x, tid = threadIdx.x;
    float mx=1e30f, my=1e30f, mz=1e30f;
    for (int n = tid; n < NPTS; n += 256) {
        const float* q = pos + ((size_t)b*NPTS + n)*3;
        mx = fminf(mx, q[0]); my = fminf(my, q[1]); mz = fminf(mz, q[2]);
    }
    __shared__ float sx[256], sy[256], sz[256];
    sx[tid]=mx; sy[tid]=my; sz[tid]=mz; __syncthreads();
    for (int o=128;o;o>>=1){ if(tid<o){sx[tid]=fminf(sx[tid],sx[tid+o]);sy[tid]=fminf(sy[tid],sy[tid+o]);sz[tid]=fminf(sz[tid],sz[tid+o]);} __syncthreads(); }
    if (tid==0){ start[b*3+0]=sx[0]; start[b*3+1]=sy[0]; start[b*3+2]=sz[0]; }
}

// ---------------- cluster id + histogram + scan + scatter ----------------
__global__ void cid_k(const float* __restrict__ pos, const float* __restrict__ start,
                      int* __restrict__ cc, int* __restrict__ hist)
{
    int p = blockIdx.x*256 + threadIdx.x;
    int b = p >> 11;
    int cx = (int)floorf((pos[p*3+0]-start[b*3+0]) / WIN);
    int cy = (int)floorf((pos[p*3+1]-start[b*3+1]) / WIN);
    int cz = (int)floorf((pos[p*3+2]-start[b*3+2]) / WIN);
    int c = (cx<<4) | (cy<<2) | cz;
    cc[p] = c;
    atomicAdd(&hist[b*64 + c], 1);
}

__global__ void scan_k(const int* __restrict__ hist, int* __restrict__ offs)
{
    int b = threadIdx.x;
    if (b < BATCH) {
        int run = 0;
        for (int c = 0; c < 64; ++c) { offs[b*64+c] = run; run += hist[b*64+c]; }
    }
}

__global__ void scatter_k(const int* __restrict__ cc, const int* __restrict__ offs,
                          int* __restrict__ cursor, int* __restrict__ sorted,
                          int* __restrict__ inv)
{
    int p = blockIdx.x*256 + threadIdx.x;
    int b = p >> 11;
    int c = cc[p];
    int r = atomicAdd(&cursor[b*64+c], 1);
    int slot = b*NPTS + offs[b*64+c] + r;
    sorted[slot] = p;
    inv[p] = slot;
}

// ---------------- weight convert+transpose: [K][N] f32 -> [N][K] bf16 --------
// QKV packed per layer as [768][256]; then Wo, W1, W2.
__global__ void wconv_k(const float* __restrict__ Wq, const float* __restrict__ Wk,
                        const float* __restrict__ Wv, const float* __restrict__ Wo,
                        const float* __restrict__ W1, const float* __restrict__ W2,
                        unsigned short* __restrict__ wT)
{
    int id = blockIdx.z; int t = id >> 1, l = id & 1;
    const float* src; unsigned short* dst; int K, N;
    switch (t) {
        case 0: src=Wq+(size_t)l*65536;  dst=wT+(size_t)l*196608;             K=256; N=256; break;
        case 1: src=Wk+(size_t)l*65536;  dst=wT+(size_t)l*196608+65536;       K=256; N=256; break;
        case 2: src=Wv+(size_t)l*65536;  dst=wT+(size_t)l*196608+131072;      K=256; N=256; break;
        case 3: src=Wo+(size_t)l*65536;  dst=wT+393216+(size_t)l*65536;       K=256; N=256; break;
        case 4: src=W1+(size_t)l*131072; dst=wT+524288+(size_t)l*131072;      K=256; N=512; break;
        default:src=W2+(size_t)l*131072; dst=wT+786432+(size_t)l*131072;      K=512; N=256; break;
    }
    int n0 = blockIdx.x*32, k0 = blockIdx.y*32;
    if (n0 >= N || k0 >= K) return;
    __shared__ float ld[32][33];
    int tid = threadIdx.x;
    #pragma unroll
    for (int i = 0; i < 4; ++i) { int v=tid+i*256; int ty=v>>5, tx=v&31;
        ld[ty][tx] = src[(size_t)(k0+ty)*N + n0+tx]; }
    __syncthreads();
    #pragma unroll
    for (int i = 0; i < 4; ++i) { int v=tid+i*256; int ny=v>>5, nk=v&31;
        dst[(size_t)(n0+ny)*K + k0+nk] = f2bf(ld[nk][ny]); }
}

__global__ void packb_k(const float* __restrict__ bq, const float* __restrict__ bk,
                        const float* __restrict__ bv, float* __restrict__ bqkv)
{
    int l = blockIdx.x, n = threadIdx.x;   // 768 threads
    float v = (n < 256) ? bq[l*256+n] : (n < 512) ? bk[l*256+n-256] : bv[l*256+n-512];
    bqkv[l*768 + n] = v;
}

// ---------------- bf16 MFMA GEMM: C = A@Wt^T + bias (+R) (+relu) -------------
template<int ACT>
__global__ __launch_bounds__(256) void bgemm_k(
    const unsigned short* __restrict__ A, const unsigned short* __restrict__ Wt,
    const float* __restrict__ bias, const float* __restrict__ R,
    float* __restrict__ Cf, unsigned short* __restrict__ Cb,
    int M, int Nc, int K)
{
    __shared__ unsigned short As[64*72];
    __shared__ unsigned short Bs[64*72];
    int tid = threadIdx.x;
    int l = tid & 63, w = tid >> 6;
    int wr = w >> 1, wc = w & 1;
    int lr = l & 15, lk = l >> 4;
    int bm = blockIdx.y * 64, bn = blockIdx.x * 64;

    f32x4 acc[2][2] = {};

    for (int k0 = 0; k0 < K; k0 += 64) {
        __syncthreads();
        #pragma unroll
        for (int i = 0; i < 2; ++i) {
            int id = tid + i*256;
            int row = id >> 3, seg = id & 7;
            ushort8 va = *(const ushort8*)&A[(size_t)(bm + row)*K + k0 + seg*8];
            *(ushort8*)&As[row*72 + seg*8] = va;
            ushort8 vb = *(const ushort8*)&Wt[(size_t)(bn + row)*K + k0 + seg*8];
            *(ushort8*)&Bs[row*72 + seg*8] = vb;
        }
        __syncthreads();
        #pragma unroll
        for (int kk = 0; kk < 64; kk += 32) {
            short8 a[2], b[2];
            #pragma unroll
            for (int mi = 0; mi < 2; ++mi)
                a[mi] = *(const short8*)&As[(wr*32 + mi*16 + lr)*72 + kk + lk*8];
            #pragma unroll
            for (int ni = 0; ni < 2; ++ni)
                b[ni] = *(const short8*)&Bs[(wc*32 + ni*16 + lr)*72 + kk + lk*8];
            #pragma unroll
            for (int mi = 0; mi < 2; ++mi)
                #pragma unroll
                for (int ni = 0; ni < 2; ++ni)
                    acc[mi][ni] = __builtin_amdgcn_mfma_f32_16x16x32_bf16(
                        a[mi], b[ni], acc[mi][ni], 0, 0, 0);
        }
    }

    #pragma unroll
    for (int mi = 0; mi < 2; ++mi) {
        #pragma unroll
        for (int ni = 0; ni < 2; ++ni) {
            #pragma unroll
            for (int r = 0; r < 4; ++r) {
                int row = bm + wr*32 + mi*16 + lk*4 + r;
                int col = bn + wc*32 + ni*16 + lr;
                float v = acc[mi][ni][r] + bias[col];
                if (R)  v += R[(size_t)row*Nc + col];
                if (ACT == 1) v = v > 0.f ? v : 0.f;
                if (Cf) Cf[(size_t)row*Nc + col] = v;
                if (Cb) Cb[(size_t)row*Nc + col] = f2bf(v);
            }
        }
    }
}

// ---------------- LayerNorm (FINAL=1 scatter-writes fp32 out) ----------------
template<int FINAL>
__global__ void ln_k(const float* __restrict__ in, const float* __restrict__ g,
                     const float* __restrict__ bta, const int* __restrict__ sorted,
                     float* __restrict__ out, unsigned short* __restrict__ outb)
{
    int row = blockIdx.x, tid = threadIdx.x;
    float v = in[(size_t)row*FDIM + tid];
    __shared__ float s1[256], s2[256];
    s1[tid]=v; s2[tid]=v*v; __syncthreads();
    for (int o=128;o;o>>=1){ if(tid<o){s1[tid]+=s1[tid+o]; s2[tid]+=s2[tid+o];} __syncthreads(); }
    float mu  = s1[0] * (1.0f/FDIM);
    float var = s2[0] * (1.0f/FDIM) - mu*mu;
    float r = g[tid]*(v-mu)*rsqrtf(var+EPSF) + bta[tid];
    if (FINAL) out[(size_t)sorted[row]*FDIM + tid] = r;
    else       out[(size_t)row*FDIM + tid] = r;
    outb[(size_t)row*FDIM + tid] = f2bf(r);
}

// ---------------- cluster-local MFMA attention ----------------
// grid (64 clusters, BATCH), 512 threads = 8 waves = 8 heads. Rows contiguous.
__global__ __launch_bounds__(512) void attn_k(
    const unsigned short* __restrict__ qkv, const int* __restrict__ offs,
    const int* __restrict__ hist, unsigned short* __restrict__ o)
{
    int cci = blockIdx.x, b = blockIdx.y;
    int Mc = hist[b*64 + cci];
    if (Mc == 0) return;
    int off = b*NPTS + offs[b*64 + cci];
    __shared__ unsigned short Kl[64*CPITCH];
    __shared__ unsigned short Vl[64*CPITCH];
    __shared__ unsigned short Pl[8][64*72];
    int tid = threadIdx.x;

    if (Mc <= 64) {
        // ---- stage K,V rows (zero-fill beyond Mc) ----
        #pragma unroll
        for (int it = 0; it < 4; ++it) {
            int id = tid + it*512;
            int key = id >> 5, ch8 = (id & 31)*8;
            ushort8 kv, vv;
            if (key < Mc) {
                kv = *(const ushort8*)&qkv[(size_t)(off+key)*768 + 256 + ch8];
                vv = *(const ushort8*)&qkv[(size_t)(off+key)*768 + 512 + ch8];
            } else {
                kv = (ushort8)0; vv = (ushort8)0;
            }
            *(ushort8*)&Kl[key*CPITCH + ch8] = kv;
            *(ushort8*)&Vl[key*CPITCH + ch8] = vv;
        }
        __syncthreads();

        int w = tid >> 6, l = tid & 63;
        int h = w;
        int lr = l & 15, lk = l >> 4;

        // ---- S = Q K^T (16 MFMA) ----
        f32x4 s[4][4] = {};
        short8 a[4], bb[4];
        #pragma unroll
        for (int mi = 0; mi < 4; ++mi) {
            int rg = off + mi*16 + lr;
            if (rg > PTS-1) rg = PTS-1;
            a[mi] = *(const short8*)&qkv[(size_t)rg*768 + h*32 + lk*8];
        }
        #pragma unroll
        for (int ni = 0; ni < 4; ++ni)
            bb[ni] = *(const short8*)&Kl[(ni*16+lr)*CPITCH + h*32 + lk*8];
        #pragma unroll
        for (int mi = 0; mi < 4; ++mi)
            #pragma unroll
            for (int ni = 0; ni < 4; ++ni)
                s[mi][ni] = __builtin_amdgcn_mfma_f32_16x16x32_bf16(a[mi], bb[ni], s[mi][ni], 0, 0, 0);

        // ---- wave-parallel softmax (rows owned by 16-lane groups) ----
        unsigned short* Pw = Pl[w];
        float invl[4][4];
        #pragma unroll
        for (int mi = 0; mi < 4; ++mi) {
            #pragma unroll
            for (int r = 0; r < 4; ++r) {
                int row = mi*16 + lk*4 + r;
                float sv[4]; float mx = -1e30f;
                #pragma unroll
                for (int ni = 0; ni < 4; ++ni) {
                    int col = ni*16 + lr;
                    float x = s[mi][ni][r] * SCALE;
                    sv[ni] = (col < Mc) ? x : -1e30f;
                    mx = fmaxf(mx, sv[ni]);
                }
                mx = fmaxf(mx, __shfl_xor(mx, 1));
                mx = fmaxf(mx, __shfl_xor(mx, 2));
                mx = fmaxf(mx, __shfl_xor(mx, 4));
                mx = fmaxf(mx, __shfl_xor(mx, 8));
                float ls = 0.f;
                #pragma unroll
                for (int ni = 0; ni < 4; ++ni) {
                    float e = __expf(sv[ni] - mx);
                    ls += e;
                    Pw[row*72 + ni*16 + lr] = f2bf(e);
                }
                ls += __shfl_xor(ls, 1);
                ls += __shfl_xor(ls, 2);
                ls += __shfl_xor(ls, 4);
                ls += __shfl_xor(ls, 8);
                invl[mi][r] = 1.0f / ls;
            }
        }

        // ---- O = P V (16 MFMA) ----
        f32x4 oacc[4][2] = {};
        #pragma unroll
        for (int ks = 0; ks < 2; ++ks) {
            short8 bv[2];
            #pragma unroll
            for (int db = 0; db < 2; ++db) {
                short8 t;
                #pragma unroll
                for (int e = 0; e < 8; ++e)
                    t[e] = (short)Vl[(ks*32 + lk*8 + e)*CPITCH + h*32 + db*16 + lr];
                bv[db] = t;
            }
            #pragma unroll
            for (int mi = 0; mi < 4; ++mi) {
                short8 pa = *(const short8*)&Pw[(mi*16+lr)*72 + ks*32 + lk*8];
                #pragma unroll
                for (int db = 0; db < 2; ++db)
                    oacc[mi][db] = __builtin_amdgcn_mfma_f32_16x16x32_bf16(pa, bv[db], oacc[mi][db], 0, 0, 0);
            }
        }

        #pragma unroll
        for (int mi = 0; mi < 4; ++mi)
            #pragma unroll
            for (int db = 0; db < 2; ++db)
                #pragma unroll
                for (int r = 0; r < 4; ++r) {
                    int row = mi*16 + lk*4 + r;
                    if (row < Mc)
                        o[(size_t)(off+row)*FDIM + h*32 + db*16 + lr] =
                            f2bf(oacc[mi][db][r] * invl[mi][r]);
                }
    } else {
        // ---- generic fallback (never taken for Poisson(32) clusters) ----
        for (int task = tid; task < Mc*NHEAD; task += 512) {
            int row = task >> 3, h = task & 7;
            float qr[DHEAD];
            #pragma unroll
            for (int d = 0; d < DHEAD; ++d)
                qr[d] = b2f(qkv[(size_t)(off+row)*768 + h*32 + d]);
            float m = -3e38f, lsum = 0.f, acc[DHEAD];
            #pragma unroll
            for (int d = 0; d < DHEAD; ++d) acc[d] = 0.f;
            for (int j = 0; j < Mc; ++j) {
                float dot = 0.f;
                #pragma unroll
                for (int d = 0; d < DHEAD; ++d)
                    dot += qr[d] * b2f(qkv[(size_t)(off+j)*768 + 256 + h*32 + d]);
                float sc = dot * SCALE;
                float mn = fmaxf(m, sc);
                float aa = __expf(m - mn);
                float e  = __expf(sc - mn);
                lsum = lsum*aa + e;
                #pragma unroll
                for (int d = 0; d < DHEAD; ++d)
                    acc[d] = acc[d]*aa + e * b2f(qkv[(size_t)(off+j)*768 + 512 + h*32 + d]);
                m = mn;
            }
            float inv = 1.0f / lsum;
            #pragma unroll
            for (int d = 0; d < DHEAD; ++d)
                o[(size_t)(off+row)*FDIM + h*32 + d] = f2bf(acc[d]*inv);
        }
    }
}

extern "C" void kernel_launch(void* const* d_in, const int* in_sizes, int n_in,
                              void* d_out, int out_size, void* d_ws, size_t ws_size,
                              hipStream_t stream)
{
    (void)in_sizes; (void)n_in; (void)out_size; (void)ws_size;
    const float* pos  = (const float*)d_in[0];
    const float* feat = (const float*)d_in[1];
    const float* kpts = (const float*)d_in[2];
    const float* kpw  = (const float*)d_in[3];
    const float* bn_g = (const float*)d_in[4];
    const float* bn_b = (const float*)d_in[5];
    const float* Wm   = (const float*)d_in[6];
    const float* Wq   = (const float*)d_in[7];
    const float* bq   = (const float*)d_in[8];
    const float* Wk   = (const float*)d_in[9];
    const float* bk   = (const float*)d_in[10];
    const float* Wv   = (const float*)d_in[11];
    const float* bv   = (const float*)d_in[12];
    const float* Wo   = (const float*)d_in[13];
    const float* bo   = (const float*)d_in[14];
    const float* g1   = (const float*)d_in[15];
    const float* be1  = (const float*)d_in[16];
    const float* W1   = (const float*)d_in[17];
    const float* bb1  = (const float*)d_in[18];
    const float* W2   = (const float*)d_in[19];
    const float* bb2  = (const float*)d_in[20];
    const float* g2   = (const float*)d_in[21];
    const float* be2  = (const float*)d_in[22];

    char* ws = (char*)d_ws;
    const size_t MB = 1024*1024;
    int*   idx    = (int*)(ws + 0);                      // 2 MB
    float* raw    = (float*)(ws + 2*MB);                 // 2 MB
    float* stats  = (float*)(ws + 4*MB);                 // 512 B
    float* start  = (float*)(ws + 4*MB + 4096);          // 48 B
    int*   cc     = (int*)(ws + 4*MB + 8192);            // 32 KB
    int*   hist   = (int*)(ws + 4*MB + 8192 + 32768);
    int*   offs   = hist + 256;
    int*   cursor = offs + 256;
    int*   sorted = (int*)(ws + 4*MB + 8192 + 32768 + 4096);   // 32 KB
    int*   inv    = sorted + PTS;                               // 32 KB
    float* xs   = (float*)(ws + 5*MB);                   // [P,256] f32 sorted
    float* t1   = (float*)(ws + 13*MB);                  // [P,256] f32
    float* x2   = (float*)(ws + 21*MB);                  // [P,256] f32
    unsigned short* xsb   = (unsigned short*)(ws + 29*MB);  // [P,256] bf16
    unsigned short* qkvb  = (unsigned short*)(ws + 33*MB);  // [P,768] bf16 (12 MB)
    unsigned short* attnb = (unsigned short*)(ws + 45*MB);  // [P,256] bf16 (also x2b)
    unsigned short* wT    = (unsigned short*)(ws + 49*MB);  // 2 MB
    float*          bqkv  = (float*)(ws + 51*MB);           // 6 KB
    unsigned short* hb    = qkvb;                            // [P,512] aliases qkv
    unsigned short* x2b   = attnb;                           // aliases attnb

    hipMemsetAsync(hist, 0, 3*256*sizeof(int), stream);

    wconv_k<<<dim3(16,16,12), 256, 0, stream>>>(Wq, Wk, Wv, Wo, W1, W2, wT);
    packb_k<<<NLAY, 768, 0, stream>>>(bq, bk, bv, bqkv);
    ball_query_k<<<PTS, 64, 0, stream>>>(pos, idx);
    kpconv_k<<<PTS/4, 256, 0, stream>>>(pos, feat, idx, kpts, kpw, raw);
    bn_stats_k<<<CKP, 256, 0, stream>>>(raw, stats);
    bmin_k<<<BATCH, 256, 0, stream>>>(pos, start);
    cid_k<<<PTS/256, 256, 0, stream>>>(pos, start, cc, hist);
    scan_k<<<1, 64, 0, stream>>>(hist, offs);
    scatter_k<<<PTS/256, 256, 0, stream>>>(cc, offs, cursor, sorted, inv);
    embed_k<<<PTS, 256, 0, stream>>>(pos, raw, stats, bn_g, bn_b, Wm, inv, xs, xsb);

    for (int l = 0; l < NLAY; ++l) {
        // fused QKV projection: [P,256] @ [256,768]
        bgemm_k<0><<<dim3(12, PTS/64), 256, 0, stream>>>(
            xsb, wT + (size_t)l*196608, bqkv + l*768, nullptr, nullptr, qkvb, PTS, 768, FDIM);
        attn_k<<<dim3(64, BATCH), 512, 0, stream>>>(qkvb, offs, hist, attnb);
        bgemm_k<0><<<dim3(4, PTS/64), 256, 0, stream>>>(
            attnb, wT + 393216 + (size_t)l*65536, bo + l*FDIM, xs, t1, nullptr, PTS, FDIM, FDIM);
        ln_k<0><<<PTS, 256, 0, stream>>>(t1, g1 + l*FDIM, be1 + l*FDIM, sorted, x2, x2b);
        bgemm_k<1><<<dim3(8, PTS/64), 256, 0, stream>>>(
            x2b, wT + 524288 + (size_t)l*131072, bb1 + l*HIDD, nullptr, nullptr, hb, PTS, HIDD, FDIM);
        bgemm_k<0><<<dim3(4, PTS/64), 256, 0, stream>>>(
            hb, wT + 786432 + (size_t)l*131072, bb2 + l*FDIM, x2, t1, nullptr, PTS, FDIM, HIDD);
        if (l == NLAY-1)
            ln_k<1><<<PTS, 256, 0, stream>>>(t1, g2 + l*FDIM, be2 + l*FDIM, sorted, (float*)d_out, xsb);
        else
            ln_k<0><<<PTS, 256, 0, stream>>>(t1, g2 + l*FDIM, be2 + l*FDIM, sorted, xs, xsb);
    }
}